// Round 8
// baseline (338.964 us; speedup 1.0000x reference)
//
#include <hip/hip_runtime.h>

#define L 2048
#define E 128
#define NB 8

typedef float f32x4 __attribute__((ext_vector_type(4)));
typedef short short8 __attribute__((ext_vector_type(8)));
typedef unsigned int u32;

static __device__ inline float bf2f(ushort u) {
  union { float f; u32 i; } v; v.i = ((u32)u) << 16; return v.f;
}
static __device__ inline ushort f2bf(float f) {
  union { float f; u32 i; } v; v.f = f;
  u32 x = v.i;
  return (ushort)((x + 0x7fffu + ((x >> 16) & 1u)) >> 16);  // RTNE
}

// async global->LDS, 16B/lane; lds dest wave-uniform base, HW adds lane*16B
__device__ inline void glds16(const ushort* g, ushort* l) {
  __builtin_amdgcn_global_load_lds(
      (const __attribute__((address_space(1))) u32*)(const void*)g,
      (__attribute__((address_space(3))) u32*)(void*)l, 16, 0, 0);
}

// ---------------------------------------------------------------------------
// prep: fp32 Uq/Uid -> bf16 UqB/UidB/Uidw; s_id/s_q fp32; out[:,:,0:128]=Uid
// ---------------------------------------------------------------------------
__global__ __launch_bounds__(128) void k_prep(const float* __restrict__ Uq,
                                              const float* __restrict__ Uid,
                                              const float* __restrict__ Wcw,
                                              ushort* __restrict__ UqB,
                                              ushort* __restrict__ UidB,
                                              ushort* __restrict__ Uidw,
                                              float* __restrict__ s_id,
                                              float* __restrict__ s_q,
                                              float* __restrict__ out) {
  int r = blockIdx.x;          // 0..B*L-1
  int e = threadIdx.x;         // 0..127
  ushort uqu  = f2bf(Uq[(long)r * E + e]);
  ushort uidu = f2bf(Uid[(long)r * E + e]);
  float uqf = bf2f(uqu), uidf = bf2f(uidu);
  float wid  = bf2f(f2bf(Wcw[e]));
  float wq   = bf2f(f2bf(Wcw[E + e]));
  float wmul = bf2f(f2bf(Wcw[2 * E + e]));
  UqB[(long)r * E + e]  = uqu;
  UidB[(long)r * E + e] = uidu;
  Uidw[(long)r * E + e] = f2bf(uidf * wmul);
  out[(long)r * 512 + e] = uidf;
  float sid = uidf * wid, sq = uqf * wq;
  #pragma unroll
  for (int off = 32; off >= 1; off >>= 1) {
    sid += __shfl_down(sid, off, 64);
    sq  += __shfl_down(sq,  off, 64);
  }
  __shared__ float red[4];
  int wv = threadIdx.x >> 6;
  if ((threadIdx.x & 63) == 0) { red[wv * 2] = sid; red[wv * 2 + 1] = sq; }
  __syncthreads();
  if (threadIdx.x == 0) { s_id[r] = red[0] + red[2]; s_q[r] = red[1] + red[3]; }
}

// ---------------------------------------------------------------------------
// maskTB: fp32 mask[i][j] -> bf16 maskT[j][i] and bf16 maskB[i][j]
// ---------------------------------------------------------------------------
__global__ __launch_bounds__(256) void k_maskTB(const float* __restrict__ mask,
                                                ushort* __restrict__ maskT,
                                                ushort* __restrict__ maskB) {
  __shared__ ushort tile[32][33];
  int j0 = blockIdx.x * 32, i0 = blockIdx.y * 32;
  int tx = threadIdx.x, ty = threadIdx.y;
  #pragma unroll
  for (int r = ty; r < 32; r += 8) {
    ushort v = f2bf(mask[(long)(i0 + r) * L + j0 + tx]);
    tile[r][tx] = v;
    maskB[(long)(i0 + r) * L + j0 + tx] = v;
  }
  __syncthreads();
  #pragma unroll
  for (int r = ty; r < 32; r += 8)
    maskT[(long)(j0 + r) * L + i0 + tx] = tile[tx][r];
}

// ---------------------------------------------------------------------------
// bf16 tile transpose: dst[c*R+r] = src[r*C+c], batched over z
// ---------------------------------------------------------------------------
__global__ __launch_bounds__(256) void k_tr(const ushort* __restrict__ src,
                                            ushort* __restrict__ dst,
                                            int R, int C) {
  __shared__ ushort tile[32][33];
  long base = (long)blockIdx.z * R * C;
  src += base; dst += base;
  int c0 = blockIdx.x * 32, r0 = blockIdx.y * 32;
  int tx = threadIdx.x, ty = threadIdx.y;
  #pragma unroll
  for (int i = ty; i < 32; i += 8)
    tile[i][tx] = src[(long)(r0 + i) * C + c0 + tx];
  __syncthreads();
  #pragma unroll
  for (int i = ty; i < 32; i += 8)
    dst[(long)(c0 + i) * R + r0 + tx] = tile[tx][i];
}

// ---------------------------------------------------------------------------
// 128x128 NT/NT K-loop (round-6 proven): BK=64, glds16.
// ---------------------------------------------------------------------------
__device__ inline void gemm128_loop(const ushort* __restrict__ A,
                                    const ushort* __restrict__ B,
                                    long ldA, long ldB, int K,
                                    f32x4 acc[4][4],
                                    ushort* ldsA, ushort* ldsB) {
  const int t = threadIdx.x;
  const int w = t >> 6, lane = t & 63;
  const int mrow = lane & 15, quad = lane >> 4;
  const int lr = lane >> 3;
  const int lc = (lane & 7) * 8;
  const int mh = (w & 1) * 64, nh = (w >> 1) * 64;
  for (int k0 = 0; k0 < K; k0 += 64) {
    __syncthreads();
    #pragma unroll
    for (int s = 0; s < 4; s++) {
      int row = w * 32 + s * 8 + lr;
      glds16(&A[(long)row * ldA + k0 + lc], &ldsA[w * 2048 + s * 512]);
      glds16(&B[(long)row * ldB + k0 + lc], &ldsB[w * 2048 + s * 512]);
    }
    __syncthreads();
    #pragma unroll
    for (int kk = 0; kk < 2; kk++) {
      short8 av[4], bv[4];
      #pragma unroll
      for (int mi = 0; mi < 4; mi++)
        av[mi] = *(const short8*)&ldsA[(mh + mi * 16 + mrow) * 64 + kk * 32 + quad * 8];
      #pragma unroll
      for (int ni = 0; ni < 4; ni++)
        bv[ni] = *(const short8*)&ldsB[(nh + ni * 16 + mrow) * 64 + kk * 32 + quad * 8];
      #pragma unroll
      for (int mi = 0; mi < 4; mi++)
        #pragma unroll
        for (int ni = 0; ni < 4; ni++)
          acc[mi][ni] = __builtin_amdgcn_mfma_f32_16x16x32_bf16(av[mi], bv[ni], acc[mi][ni], 0, 0, 0);
    }
  }
}

// ---------------------------------------------------------------------------
// scores (round-6 proven): St[bz,j,i] = (dot+sq+sid+bias)*maskT[j,i]
// ---------------------------------------------------------------------------
__global__ __launch_bounds__(256) void k_scores(const ushort* __restrict__ Uq,
                                                const ushort* __restrict__ Uidw,
                                                const float* __restrict__ s_id,
                                                const float* __restrict__ s_q,
                                                const float* __restrict__ Wcb,
                                                const ushort* __restrict__ maskT,
                                                ushort* __restrict__ St, int b0) {
  __shared__ ushort ldsA[128 * 64];
  __shared__ ushort ldsB[128 * 64];
  int bz = blockIdx.z, b = b0 + bz;
  int m0 = blockIdx.x * 128;   // j
  int n0 = blockIdx.y * 128;   // i
  const ushort* A = Uq   + (long)b * L * E + (long)m0 * E;
  const ushort* B = Uidw + (long)b * L * E + (long)n0 * E;
  f32x4 acc[4][4] = {};
  gemm128_loop(A, B, E, E, E, acc, ldsA, ldsB);
  float bias = bf2f(f2bf(Wcb[0]));
  const int t = threadIdx.x, w = t >> 6, lane = t & 63;
  const int col = lane & 15, quad = lane >> 4;
  const int mh = (w & 1) * 64, nh = (w >> 1) * 64;
  #pragma unroll
  for (int mi = 0; mi < 4; mi++)
    #pragma unroll
    for (int ni = 0; ni < 4; ni++) {
      int ig = n0 + nh + ni * 16 + col;
      float sidv = s_id[b * L + ig];
      #pragma unroll
      for (int rg = 0; rg < 4; rg++) {
        int jg = m0 + mh + mi * 16 + quad * 4 + rg;
        float v = (acc[mi][ni][rg] + s_q[b * L + jg] + sidv + bias)
                  * bf2f(maskT[(long)jg * L + ig]);
        St[(long)bz * L * L + (long)jg * L + ig] = f2bf(v);
      }
    }
}

// ---------------------------------------------------------------------------
// stats: per St row j -> mstat = max_i, lstat = 1/sum exp. Block = 32 rows.
// ---------------------------------------------------------------------------
__global__ __launch_bounds__(256) void k_stats(const ushort* __restrict__ St,
                                               float* __restrict__ mstat,
                                               float* __restrict__ lstat, int b0) {
  int bz = blockIdx.y, b = b0 + bz;
  int j0 = blockIdx.x * 32;
  const ushort* Sb = St + (long)bz * L * L;
  int t = threadIdx.x, w = t >> 6, lane = t & 63;
  for (int rr = w; rr < 32; rr += 4) {
    const ushort* row = Sb + (long)(j0 + rr) * L;
    uint4 q[4];
    #pragma unroll
    for (int c = 0; c < 4; c++) q[c] = *(const uint4*)&row[lane * 8 + c * 512];
    float v[32]; float mx = -1e30f;
    #pragma unroll
    for (int c = 0; c < 4; c++) {
      ushort* pr = (ushort*)&q[c];
      #pragma unroll
      for (int k = 0; k < 8; k++) { v[c * 8 + k] = bf2f(pr[k]); mx = fmaxf(mx, v[c * 8 + k]); }
    }
    #pragma unroll
    for (int off = 32; off >= 1; off >>= 1) mx = fmaxf(mx, __shfl_xor(mx, off, 64));
    float s = 0.f;
    #pragma unroll
    for (int k = 0; k < 32; k++) s += __expf(v[k] - mx);
    #pragma unroll
    for (int off = 32; off >= 1; off >>= 1) s += __shfl_xor(s, off, 64);
    if (lane == 0) {
      mstat[(long)b * L + j0 + rr] = mx;
      lstat[(long)b * L + j0 + rr] = 1.0f / s;
    }
  }
}

// ---------------------------------------------------------------------------
// ft: Tt[b,e,j] = sum_i P[j,i]*Uid[i,e], P = exp(St - m_j)*linv_j applied in
// the A-fragment unpack. M=64 j, N=128 e, K=i loop (64-chunks).
// ---------------------------------------------------------------------------
__global__ __launch_bounds__(256) void k_ft(const ushort* __restrict__ St,
                                            const ushort* __restrict__ UidT,
                                            const float* __restrict__ mstat,
                                            const float* __restrict__ lstat,
                                            ushort* __restrict__ Tt, int b0) {
  __shared__ ushort ldsP[64 * 64];    // St tile [j][i]
  __shared__ ushort ldsB[128 * 64];   // UidT tile [e][i]
  __shared__ float sm[64], sl[64];
  int bz = blockIdx.y, b = b0 + bz;
  int j0 = blockIdx.x * 64;
  int t = threadIdx.x, w = t >> 6, lane = t & 63;
  int mrow = lane & 15, quad = lane >> 4;
  int mh = (w & 1) * 32, nh = (w >> 1) * 64;
  if (t < 64) {
    sm[t] = mstat[(long)b * L + j0 + t];
    sl[t] = lstat[(long)b * L + j0 + t];
  }
  const ushort* Sb = St + (long)bz * L * L;
  const ushort* Ub = UidT + (long)b * E * L;
  f32x4 acc[2][4] = {};
  for (int i0 = 0; i0 < L; i0 += 64) {
    __syncthreads();
    #pragma unroll
    for (int s = 0; s < 2; s++) {
      int row = w * 16 + s * 8 + (lane >> 3);
      glds16(&Sb[(long)(j0 + row) * L + i0 + (lane & 7) * 8], &ldsP[(w * 16 + s * 8) * 64]);
    }
    #pragma unroll
    for (int s = 0; s < 4; s++) {
      int row = w * 32 + s * 8 + (lane >> 3);
      glds16(&Ub[(long)row * L + i0 + (lane & 7) * 8], &ldsB[(w * 32 + s * 8) * 64]);
    }
    __syncthreads();
    #pragma unroll
    for (int kk = 0; kk < 2; kk++) {
      short8 av[2], bv[4];
      #pragma unroll
      for (int mi = 0; mi < 2; mi++) {
        int jl = mh + mi * 16 + mrow;
        short8 raw = *(const short8*)&ldsP[jl * 64 + kk * 32 + quad * 8];
        float m = sm[jl], linv = sl[jl];
        ushort o[8];
        ushort* pr = (ushort*)&raw;
        #pragma unroll
        for (int u = 0; u < 8; u++) o[u] = f2bf(__expf(bf2f(pr[u]) - m) * linv);
        av[mi] = *(short8*)o;
      }
      #pragma unroll
      for (int ni = 0; ni < 4; ni++)
        bv[ni] = *(const short8*)&ldsB[(nh + ni * 16 + mrow) * 64 + kk * 32 + quad * 8];
      #pragma unroll
      for (int mi = 0; mi < 2; mi++)
        #pragma unroll
        for (int ni = 0; ni < 4; ni++)
          acc[mi][ni] = __builtin_amdgcn_mfma_f32_16x16x32_bf16(av[mi], bv[ni], acc[mi][ni], 0, 0, 0);
    }
  }
  #pragma unroll
  for (int mi = 0; mi < 2; mi++)
    #pragma unroll
    for (int ni = 0; ni < 4; ni++) {
      int e = nh + ni * 16 + (lane & 15);
      int jb = j0 + mh + mi * 16 + quad * 4;
      ushort o[4];
      #pragma unroll
      for (int rg = 0; rg < 4; rg++) o[rg] = f2bf(acc[mi][ni][rg]);
      *(uint2*)&Tt[(long)b * E * L + (long)e * L + jb] = *(uint2*)o;
    }
}

// ---------------------------------------------------------------------------
// fa: out cols 128..511. Recompute S'[i,j] (A=Uidw,B=Uq,K=E), P via stats,
// LDS C->A round trip, then acc2 += P @ X^T (X^T = UqT or Tt), K=j loop.
// ---------------------------------------------------------------------------
__global__ __launch_bounds__(256) void k_fa(const ushort* __restrict__ Uidw,
                                            const ushort* __restrict__ UqB,
                                            const ushort* __restrict__ UqT,
                                            const ushort* __restrict__ Tt,
                                            const ushort* __restrict__ maskB,
                                            const float* __restrict__ mstat,
                                            const float* __restrict__ lstat,
                                            const float* __restrict__ s_id,
                                            const float* __restrict__ s_q,
                                            const float* __restrict__ Wcb,
                                            const ushort* __restrict__ UidB,
                                            float* __restrict__ out, int b0) {
  __shared__ ushort ldsA[64 * 128];   // Uidw [i][e]   16K (staged once)
  __shared__ ushort ldsB[64 * 128];   // Uq   [j][e]   16K
  __shared__ ushort ldsM[64 * 64];    // mask [i][j]    8K
  __shared__ ushort ldsX[128 * 64];   // X^T  [c][j]   16K
  __shared__ ushort ldsP[64 * 72];    // P    [i][j]    9K (pad 72)
  __shared__ float si[64], sjm[64], sjl[64], sjq[64];
  int bz = blockIdx.z, b = b0 + bz;
  int i0 = blockIdx.x * 64;
  int cbase = blockIdx.y * 128;
  const ushort* Xb = (blockIdx.y == 0 ? UqT : Tt) + (long)b * E * L;
  int t = threadIdx.x, w = t >> 6, lane = t & 63;
  int mrow = lane & 15, quad = lane >> 4;
  int mh = (w & 1) * 32, nh1 = (w >> 1) * 32, nh2 = (w >> 1) * 64;
  if (t < 64) si[t] = s_id[(long)b * L + i0 + t];
  #pragma unroll
  for (int s = 0; s < 4; s++) {
    int row = w * 16 + s * 4 + (lane >> 4);
    glds16(&Uidw[(long)b * L * E + (long)(i0 + row) * E + (lane & 15) * 8],
           &ldsA[(w * 16 + s * 4) * 128]);
  }
  float bias = bf2f(f2bf(Wcb[0]));
  f32x4 acc2[2][4] = {};
  for (int j0 = 0; j0 < L; j0 += 64) {
    __syncthreads();   // prior iter readers (ldsB/M/X/P) done; ldsA DMA drained on iter 0
    #pragma unroll
    for (int s = 0; s < 4; s++) {
      int row = w * 16 + s * 4 + (lane >> 4);
      glds16(&UqB[(long)b * L * E + (long)(j0 + row) * E + (lane & 15) * 8],
             &ldsB[(w * 16 + s * 4) * 128]);
    }
    #pragma unroll
    for (int s = 0; s < 2; s++) {
      int row = w * 16 + s * 8 + (lane >> 3);
      glds16(&maskB[(long)(i0 + row) * L + j0 + (lane & 7) * 8],
             &ldsM[(w * 16 + s * 8) * 64]);
    }
    #pragma unroll
    for (int s = 0; s < 4; s++) {
      int row = w * 32 + s * 8 + (lane >> 3);
      glds16(&Xb[(long)row * L + j0 + (lane & 7) * 8], &ldsX[(w * 32 + s * 8) * 64]);
    }
    if (t < 64) {
      sjm[t] = mstat[(long)b * L + j0 + t];
      sjl[t] = lstat[(long)b * L + j0 + t];
      sjq[t] = s_q[(long)b * L + j0 + t];
    }
    __syncthreads();
    // S' tile: M=64 i, N=64 j, K=128 e
    f32x4 a1[2][2] = {};
    #pragma unroll
    for (int kk = 0; kk < 4; kk++) {
      short8 av[2], bv[2];
      #pragma unroll
      for (int mi = 0; mi < 2; mi++)
        av[mi] = *(const short8*)&ldsA[(mh + mi * 16 + mrow) * 128 + kk * 32 + quad * 8];
      #pragma unroll
      for (int ni = 0; ni < 2; ni++)
        bv[ni] = *(const short8*)&ldsB[(nh1 + ni * 16 + mrow) * 128 + kk * 32 + quad * 8];
      #pragma unroll
      for (int mi = 0; mi < 2; mi++)
        #pragma unroll
        for (int ni = 0; ni < 2; ni++)
          a1[mi][ni] = __builtin_amdgcn_mfma_f32_16x16x32_bf16(av[mi], bv[ni], a1[mi][ni], 0, 0, 0);
    }
    // P = exp((S'+si+sq+bias)*mask - m_j)*linv_j  -> ldsP[i][j]
    #pragma unroll
    for (int mi = 0; mi < 2; mi++)
      #pragma unroll
      for (int ni = 0; ni < 2; ni++)
        #pragma unroll
        for (int rg = 0; rg < 4; rg++) {
          int il = mh + mi * 16 + quad * 4 + rg;
          int jl = nh1 + ni * 16 + (lane & 15);
          float v = (a1[mi][ni][rg] + si[il] + sjq[jl] + bias) * bf2f(ldsM[il * 64 + jl]);
          float p = __expf(v - sjm[jl]) * sjl[jl];
          ldsP[il * 72 + jl] = f2bf(p);
        }
    __syncthreads();
    // acc2 += P @ X^T : M=64 i, N=128 c, K=64 j
    #pragma unroll
    for (int kk = 0; kk < 2; kk++) {
      short8 av2[2], bv2[4];
      #pragma unroll
      for (int mi = 0; mi < 2; mi++)
        av2[mi] = *(const short8*)&ldsP[(mh + mi * 16 + mrow) * 72 + kk * 32 + quad * 8];
      #pragma unroll
      for (int ni = 0; ni < 4; ni++)
        bv2[ni] = *(const short8*)&ldsX[(nh2 + ni * 16 + mrow) * 64 + kk * 32 + quad * 8];
      #pragma unroll
      for (int mi = 0; mi < 2; mi++)
        #pragma unroll
        for (int ni = 0; ni < 4; ni++)
          acc2[mi][ni] = __builtin_amdgcn_mfma_f32_16x16x32_bf16(av2[mi], bv2[ni], acc2[mi][ni], 0, 0, 0);
    }
  }
  #pragma unroll
  for (int mi = 0; mi < 2; mi++)
    #pragma unroll
    for (int ni = 0; ni < 4; ni++)
      #pragma unroll
      for (int rg = 0; rg < 4; rg++) {
        int ig = i0 + mh + mi * 16 + quad * 4 + rg;
        int c  = cbase + nh2 + ni * 16 + (lane & 15);
        float a = acc2[mi][ni][rg];
        float uidf = bf2f(UidB[(long)b * L * E + (long)ig * E + (c & 127)]);
        long ob = ((long)b * L + ig) * 512;
        if (c < 128) { out[ob + 128 + c] = a; out[ob + 256 + c] = uidf * a; }
        else         { out[ob + 256 + c] = uidf * a; }
      }
}

// ---------------------------------------------------------------------------
extern "C" void kernel_launch(void* const* d_in, const int* in_sizes, int n_in,
                              void* d_out, int out_size, void* d_ws, size_t ws_size,
                              hipStream_t stream) {
  const float* Uq   = (const float*)d_in[0];
  const float* Uid  = (const float*)d_in[1];
  const float* mask = (const float*)d_in[2];
  const float* Wcw  = (const float*)d_in[3];
  const float* Wcb  = (const float*)d_in[4];
  float* out = (float*)d_out;

  char* ws = (char*)d_ws;
  size_t off = 0;
  auto alloc = [&](size_t bytes) -> void* {
    void* p = ws + off; off += (bytes + 255) & ~(size_t)255; return p;
  };
  const size_t nUb = (size_t)NB * L * E * 2;
  ushort* UqB   = (ushort*)alloc(nUb);
  ushort* UidB  = (ushort*)alloc(nUb);
  ushort* Uidw  = (ushort*)alloc(nUb);
  ushort* UqT   = (ushort*)alloc(nUb);
  ushort* UidT  = (ushort*)alloc(nUb);
  ushort* Tt    = (ushort*)alloc(nUb);
  ushort* maskT = (ushort*)alloc((size_t)L * L * 2);
  ushort* maskB = (ushort*)alloc((size_t)L * L * 2);
  float*  s_id  = (float*)alloc((size_t)NB * L * 4);
  float*  s_q   = (float*)alloc((size_t)NB * L * 4);
  float*  mstat = (float*)alloc((size_t)NB * L * 4);
  float*  lstat = (float*)alloc((size_t)NB * L * 4);
  // fixed ~42.5 MB; St chunk: nb_c * 8.4 MB
  const size_t per_batch = (size_t)L * L * 2;
  size_t avail = (ws_size > off + per_batch) ? (ws_size - off) : per_batch;
  int nb_c = (int)(avail / per_batch);
  if (nb_c < 1) nb_c = 1;
  if (nb_c > NB) nb_c = NB;
  ushort* St = (ushort*)(ws + off);

  dim3 tb(32, 8);
  k_prep<<<NB * L, E, 0, stream>>>(Uq, Uid, Wcw, UqB, UidB, Uidw, s_id, s_q, out);
  k_maskTB<<<dim3(L / 32, L / 32), tb, 0, stream>>>(mask, maskT, maskB);
  k_tr<<<dim3(E / 32, L / 32, NB), tb, 0, stream>>>(UqB, UqT, L, E);
  k_tr<<<dim3(E / 32, L / 32, NB), tb, 0, stream>>>(UidB, UidT, L, E);

  for (int b0 = 0; b0 < NB; b0 += nb_c) {
    int nb = (NB - b0 < nb_c) ? (NB - b0) : nb_c;
    k_scores<<<dim3(L / 128, L / 128, nb), 256, 0, stream>>>(UqB, Uidw, s_id, s_q, Wcb, maskT, St, b0);
    k_stats<<<dim3(L / 32, nb), 256, 0, stream>>>(St, mstat, lstat, b0);
    k_ft<<<dim3(L / 64, nb), 256, 0, stream>>>(St, UidT, mstat, lstat, Tt, b0);
    k_fa<<<dim3(L / 64, 2, nb), 256, 0, stream>>>(Uidw, UqB, UqT, Tt, maskB, mstat, lstat,
                                                  s_id, s_q, Wcb, UidB, out, b0);
  }
}

// Round 9
// 270.319 us; speedup vs baseline: 1.2539x; 1.2539x over previous
//
#include <hip/hip_runtime.h>

#define L 2048
#define E 128
#define NB 8

typedef float f32x4 __attribute__((ext_vector_type(4)));
typedef short short8 __attribute__((ext_vector_type(8)));
typedef unsigned int u32;

static __device__ inline float bf2f(ushort u) {
  union { float f; u32 i; } v; v.i = ((u32)u) << 16; return v.f;
}
static __device__ inline ushort f2bf(float f) {
  union { float f; u32 i; } v; v.f = f;
  u32 x = v.i;
  return (ushort)((x + 0x7fffu + ((x >> 16) & 1u)) >> 16);  // RTNE
}

// async global->LDS, 16B/lane; lds dest wave-uniform base, HW adds lane*16B
__device__ inline void glds16(const ushort* g, ushort* l) {
  __builtin_amdgcn_global_load_lds(
      (const __attribute__((address_space(1))) u32*)(const void*)g,
      (__attribute__((address_space(3))) u32*)(void*)l, 16, 0, 0);
}

// ---------------------------------------------------------------------------
// prep: fp32 Uq/Uid -> bf16 UqB/UidB/Uidw; s_id/s_q fp32
// (out[:,:,0:128] is written by k_gemm_A's y==0 epilogue)
// ---------------------------------------------------------------------------
__global__ __launch_bounds__(128) void k_prep(const float* __restrict__ Uq,
                                              const float* __restrict__ Uid,
                                              const float* __restrict__ Wcw,
                                              ushort* __restrict__ UqB,
                                              ushort* __restrict__ UidB,
                                              ushort* __restrict__ Uidw,
                                              float* __restrict__ s_id,
                                              float* __restrict__ s_q) {
  int r = blockIdx.x;          // 0..B*L-1
  int e = threadIdx.x;         // 0..127
  ushort uqu  = f2bf(Uq[(long)r * E + e]);
  ushort uidu = f2bf(Uid[(long)r * E + e]);
  float uqf = bf2f(uqu), uidf = bf2f(uidu);
  float wid  = bf2f(f2bf(Wcw[e]));
  float wq   = bf2f(f2bf(Wcw[E + e]));
  float wmul = bf2f(f2bf(Wcw[2 * E + e]));
  UqB[(long)r * E + e]  = uqu;
  UidB[(long)r * E + e] = uidu;
  Uidw[(long)r * E + e] = f2bf(uidf * wmul);
  float sid = uidf * wid, sq = uqf * wq;
  #pragma unroll
  for (int off = 32; off >= 1; off >>= 1) {
    sid += __shfl_down(sid, off, 64);
    sq  += __shfl_down(sq,  off, 64);
  }
  __shared__ float red[4];
  int wv = threadIdx.x >> 6;
  if ((threadIdx.x & 63) == 0) { red[wv * 2] = sid; red[wv * 2 + 1] = sq; }
  __syncthreads();
  if (threadIdx.x == 0) { s_id[r] = red[0] + red[2]; s_q[r] = red[1] + red[3]; }
}

// ---------------------------------------------------------------------------
// maskT: fp32 mask[i][j] -> bf16 maskT[j][i]
// ---------------------------------------------------------------------------
__global__ __launch_bounds__(256) void k_maskT(const float* __restrict__ mask,
                                               ushort* __restrict__ maskT) {
  __shared__ ushort tile[32][33];
  int j0 = blockIdx.x * 32, i0 = blockIdx.y * 32;
  int tx = threadIdx.x, ty = threadIdx.y;
  #pragma unroll
  for (int r = ty; r < 32; r += 8)
    tile[r][tx] = f2bf(mask[(long)(i0 + r) * L + j0 + tx]);
  __syncthreads();
  #pragma unroll
  for (int r = ty; r < 32; r += 8)
    maskT[(long)(j0 + r) * L + i0 + tx] = tile[tx][r];
}

// ---------------------------------------------------------------------------
// bf16 tile transpose: dst[c*R+r] = src[r*C+c], batched over z
// ---------------------------------------------------------------------------
__global__ __launch_bounds__(256) void k_tr(const ushort* __restrict__ src,
                                            ushort* __restrict__ dst,
                                            int R, int C) {
  __shared__ ushort tile[32][33];
  long base = (long)blockIdx.z * R * C;
  src += base; dst += base;
  int c0 = blockIdx.x * 32, r0 = blockIdx.y * 32;
  int tx = threadIdx.x, ty = threadIdx.y;
  #pragma unroll
  for (int i = ty; i < 32; i += 8)
    tile[i][tx] = src[(long)(r0 + i) * C + c0 + tx];
  __syncthreads();
  #pragma unroll
  for (int i = ty; i < 32; i += 8)
    dst[(long)(c0 + i) * R + r0 + tx] = tile[tx][i];
}

// ---------------------------------------------------------------------------
// 128x128 NT/NT K-loop: BK=64, glds16.
// ---------------------------------------------------------------------------
__device__ inline void gemm128_loop(const ushort* __restrict__ A,
                                    const ushort* __restrict__ B,
                                    long ldA, long ldB, int K,
                                    f32x4 acc[4][4],
                                    ushort* ldsA, ushort* ldsB) {
  const int t = threadIdx.x;
  const int w = t >> 6, lane = t & 63;
  const int mrow = lane & 15, quad = lane >> 4;
  const int lr = lane >> 3;
  const int lc = (lane & 7) * 8;
  const int mh = (w & 1) * 64, nh = (w >> 1) * 64;
  for (int k0 = 0; k0 < K; k0 += 64) {
    __syncthreads();
    #pragma unroll
    for (int s = 0; s < 4; s++) {
      int row = w * 32 + s * 8 + lr;
      glds16(&A[(long)row * ldA + k0 + lc], &ldsA[w * 2048 + s * 512]);
      glds16(&B[(long)row * ldB + k0 + lc], &ldsB[w * 2048 + s * 512]);
    }
    __syncthreads();
    #pragma unroll
    for (int kk = 0; kk < 2; kk++) {
      short8 av[4], bv[4];
      #pragma unroll
      for (int mi = 0; mi < 4; mi++)
        av[mi] = *(const short8*)&ldsA[(mh + mi * 16 + mrow) * 64 + kk * 32 + quad * 8];
      #pragma unroll
      for (int ni = 0; ni < 4; ni++)
        bv[ni] = *(const short8*)&ldsB[(nh + ni * 16 + mrow) * 64 + kk * 32 + quad * 8];
      #pragma unroll
      for (int mi = 0; mi < 4; mi++)
        #pragma unroll
        for (int ni = 0; ni < 4; ni++)
          acc[mi][ni] = __builtin_amdgcn_mfma_f32_16x16x32_bf16(av[mi], bv[ni], acc[mi][ni], 0, 0, 0);
    }
  }
}

// ---------------------------------------------------------------------------
// 64x128 (MxN) NT/NT K-loop: BK=64, glds16.
// ---------------------------------------------------------------------------
__device__ inline void gemm64x128_loop(const ushort* __restrict__ A,
                                       const ushort* __restrict__ B,
                                       long ldA, long ldB, int K,
                                       f32x4 acc[2][4],
                                       ushort* ldsA, ushort* ldsB) {
  const int t = threadIdx.x;
  const int w = t >> 6, lane = t & 63;
  const int mrow = lane & 15, quad = lane >> 4;
  const int lr = lane >> 3;
  const int lc = (lane & 7) * 8;
  const int mh = (w & 1) * 32, nh = (w >> 1) * 64;
  for (int k0 = 0; k0 < K; k0 += 64) {
    __syncthreads();
    #pragma unroll
    for (int s = 0; s < 2; s++) {
      int row = w * 16 + s * 8 + lr;
      glds16(&A[(long)row * ldA + k0 + lc], &ldsA[w * 1024 + s * 512]);
    }
    #pragma unroll
    for (int s = 0; s < 4; s++) {
      int row = w * 32 + s * 8 + lr;
      glds16(&B[(long)row * ldB + k0 + lc], &ldsB[w * 2048 + s * 512]);
    }
    __syncthreads();
    #pragma unroll
    for (int kk = 0; kk < 2; kk++) {
      short8 av[2], bv[4];
      #pragma unroll
      for (int mi = 0; mi < 2; mi++)
        av[mi] = *(const short8*)&ldsA[(mh + mi * 16 + mrow) * 64 + kk * 32 + quad * 8];
      #pragma unroll
      for (int ni = 0; ni < 4; ni++)
        bv[ni] = *(const short8*)&ldsB[(nh + ni * 16 + mrow) * 64 + kk * 32 + quad * 8];
      #pragma unroll
      for (int mi = 0; mi < 2; mi++)
        #pragma unroll
        for (int ni = 0; ni < 4; ni++)
          acc[mi][ni] = __builtin_amdgcn_mfma_f32_16x16x32_bf16(av[mi], bv[ni], acc[mi][ni], 0, 0, 0);
    }
  }
}

// ---------------------------------------------------------------------------
// scores (round-6 proven): St[bz,j,i] = (dot+sq+sid+bias)*maskT[j,i]
// ---------------------------------------------------------------------------
__global__ __launch_bounds__(256) void k_scores(const ushort* __restrict__ Uq,
                                                const ushort* __restrict__ Uidw,
                                                const float* __restrict__ s_id,
                                                const float* __restrict__ s_q,
                                                const float* __restrict__ Wcb,
                                                const ushort* __restrict__ maskT,
                                                ushort* __restrict__ St, int b0) {
  __shared__ ushort ldsA[128 * 64];
  __shared__ ushort ldsB[128 * 64];
  int bz = blockIdx.z, b = b0 + bz;
  int m0 = blockIdx.x * 128;   // j
  int n0 = blockIdx.y * 128;   // i
  const ushort* A = Uq   + (long)b * L * E + (long)m0 * E;
  const ushort* B = Uidw + (long)b * L * E + (long)n0 * E;
  f32x4 acc[4][4] = {};
  gemm128_loop(A, B, E, E, E, acc, ldsA, ldsB);
  float bias = bf2f(f2bf(Wcb[0]));
  const int t = threadIdx.x, w = t >> 6, lane = t & 63;
  const int col = lane & 15, quad = lane >> 4;
  const int mh = (w & 1) * 64, nh = (w >> 1) * 64;
  #pragma unroll
  for (int mi = 0; mi < 4; mi++)
    #pragma unroll
    for (int ni = 0; ni < 4; ni++) {
      int ig = n0 + nh + ni * 16 + col;
      float sidv = s_id[b * L + ig];
      #pragma unroll
      for (int rg = 0; rg < 4; rg++) {
        int jg = m0 + mh + mi * 16 + quad * 4 + rg;
        float v = (acc[mi][ni][rg] + s_q[b * L + jg] + sidv + bias)
                  * bf2f(maskT[(long)jg * L + ig]);
        St[(long)bz * L * L + (long)jg * L + ig] = f2bf(v);
      }
    }
}

// ---------------------------------------------------------------------------
// fused softmax + transpose (round-7 proven): St rows -> Pt (in place) + P
// ---------------------------------------------------------------------------
__global__ __launch_bounds__(256) void k_softmax_tr(ushort* __restrict__ St,
                                                    ushort* __restrict__ P) {
  int bz = blockIdx.y;
  int j0 = blockIdx.x * 32;
  ushort* Sb = St + (long)bz * L * L;
  ushort* Pb = P  + (long)bz * L * L;
  int t = threadIdx.x, w = t >> 6, lane = t & 63;
  __shared__ float mrow[32], lrow[32];
  __shared__ ushort tile[128 * 33];
  for (int rr = w; rr < 32; rr += 4) {
    const ushort* row = Sb + (long)(j0 + rr) * L;
    uint4 q[4];
    #pragma unroll
    for (int c = 0; c < 4; c++) q[c] = *(const uint4*)&row[lane * 8 + c * 512];
    float v[32]; float mx = -1e30f;
    #pragma unroll
    for (int c = 0; c < 4; c++) {
      ushort* pr = (ushort*)&q[c];
      #pragma unroll
      for (int k = 0; k < 8; k++) { v[c * 8 + k] = bf2f(pr[k]); mx = fmaxf(mx, v[c * 8 + k]); }
    }
    #pragma unroll
    for (int off = 32; off >= 1; off >>= 1) mx = fmaxf(mx, __shfl_xor(mx, off, 64));
    float s = 0.f;
    #pragma unroll
    for (int k = 0; k < 32; k++) s += __expf(v[k] - mx);
    #pragma unroll
    for (int off = 32; off >= 1; off >>= 1) s += __shfl_xor(s, off, 64);
    if (lane == 0) { mrow[rr] = mx; lrow[rr] = 1.0f / s; }
  }
  __syncthreads();
  int r = t >> 3, c0 = (t & 7) * 16;
  float m = mrow[r], inv = lrow[r];
  int il = t >> 1, half = (t & 1) * 16;
  for (int i0 = 0; i0 < L; i0 += 128) {
    ushort* src = Sb + (long)(j0 + r) * L + i0 + c0;
    uint4 q0 = *(const uint4*)src;
    uint4 q1 = *(const uint4*)(src + 8);
    ushort o[16];
    ushort* pr = (ushort*)&q0;
    #pragma unroll
    for (int k = 0; k < 8; k++) o[k] = f2bf(__expf(bf2f(pr[k]) - m) * inv);
    pr = (ushort*)&q1;
    #pragma unroll
    for (int k = 0; k < 8; k++) o[8 + k] = f2bf(__expf(bf2f(pr[k]) - m) * inv);
    *(uint4*)src = *(uint4*)&o[0];
    *(uint4*)(src + 8) = *(uint4*)&o[8];
    __syncthreads();
    #pragma unroll
    for (int k = 0; k < 16; k++) tile[(c0 + k) * 33 + r] = o[k];
    __syncthreads();
    ushort po[16];
    #pragma unroll
    for (int jj = 0; jj < 16; jj++) po[jj] = tile[il * 33 + half + jj];
    ushort* pd = Pb + (long)(i0 + il) * L + j0 + half;
    *(uint4*)pd = *(uint4*)&po[0];
    *(uint4*)(pd + 8) = *(uint4*)&po[8];
  }
}

// ---------------------------------------------------------------------------
// gemm_Tt (64x128): Tt[b,e,j] = sum_i UidT[b,e,i] * Pt[bz,j,i]
// A = UidT rows e (M=64 tile), B = Pt rows j (N=128 tile); writes Tt directly.
// ---------------------------------------------------------------------------
__global__ __launch_bounds__(256) void k_gemm_Tt(const ushort* __restrict__ UidT,
                                                 const ushort* __restrict__ Pt,
                                                 ushort* __restrict__ Tt, int b0) {
  __shared__ ushort ldsA[64 * 64];
  __shared__ ushort ldsB[128 * 64];
  int bz = blockIdx.z, b = b0 + bz;
  int e0 = (blockIdx.x & 1) * 64;        // e tile
  int j0 = (blockIdx.x >> 1) * 128;      // j tile
  const ushort* A = UidT + (long)b * E * L + (long)e0 * L;
  const ushort* B = Pt   + (long)bz * L * L + (long)j0 * L;
  f32x4 acc[2][4] = {};
  gemm64x128_loop(A, B, L, L, L, acc, ldsA, ldsB);
  const int t = threadIdx.x, w = t >> 6, lane = t & 63;
  const int col = lane & 15, quad = lane >> 4;
  const int mh = (w & 1) * 32, nh = (w >> 1) * 64;
  #pragma unroll
  for (int mi = 0; mi < 2; mi++)
    #pragma unroll
    for (int ni = 0; ni < 4; ni++)
      #pragma unroll
      for (int rg = 0; rg < 4; rg++) {
        int eg = e0 + mh + mi * 16 + quad * 4 + rg;
        int jg = j0 + nh + ni * 16 + col;
        Tt[(long)b * E * L + (long)eg * L + jg] = f2bf(acc[mi][ni][rg]);
      }
}

// ---------------------------------------------------------------------------
// gemm_A (64x128): C[b,i,c] = sum_j P[bz,i,j] * X^T[c,j], X^T = UqT | Tt
// epilogue -> out cols 128..511 (fp32); y==0 also writes out cols 0..127=Uid
// ---------------------------------------------------------------------------
__global__ __launch_bounds__(256) void k_gemm_A(const ushort* __restrict__ P,
                                                const ushort* __restrict__ UqT,
                                                const ushort* __restrict__ Tt,
                                                const ushort* __restrict__ UidB,
                                                float* __restrict__ out, int b0) {
  __shared__ ushort ldsA[64 * 64];
  __shared__ ushort ldsB[128 * 64];
  int bz = blockIdx.z, b = b0 + bz;
  int m0 = blockIdx.x * 64;    // i
  int n0 = blockIdx.y * 128;   // c base: 0 -> Uq, 128 -> T
  const ushort* A = P + (long)bz * L * L + (long)m0 * L;
  const ushort* B = (blockIdx.y == 0) ? (UqT + (long)b * E * L)
                                      : (Tt  + (long)b * E * L);
  f32x4 acc[2][4] = {};
  gemm64x128_loop(A, B, L, L, L, acc, ldsA, ldsB);
  const int t = threadIdx.x, w = t >> 6, lane = t & 63;
  const int col = lane & 15, quad = lane >> 4;
  const int mh = (w & 1) * 32, nh = (w >> 1) * 64;
  #pragma unroll
  for (int mi = 0; mi < 2; mi++)
    #pragma unroll
    for (int ni = 0; ni < 4; ni++)
      #pragma unroll
      for (int rg = 0; rg < 4; rg++) {
        int ig = m0 + mh + mi * 16 + quad * 4 + rg;
        int c  = n0 + nh + ni * 16 + col;
        float a = acc[mi][ni][rg];
        float uidf = bf2f(UidB[(long)b * L * E + (long)ig * E + (c & 127)]);
        long ob = ((long)b * L + ig) * 512;
        if (c < 128) {
          out[ob + c]       = uidf;        // Vid identity block
          out[ob + 128 + c] = a;           // A_D2Q
          out[ob + 256 + c] = uidf * a;    // Uid * A_D2Q
        } else {
          out[ob + 256 + c] = uidf * a;    // Uid * A_Q2D
        }
      }
}

// ---------------------------------------------------------------------------
extern "C" void kernel_launch(void* const* d_in, const int* in_sizes, int n_in,
                              void* d_out, int out_size, void* d_ws, size_t ws_size,
                              hipStream_t stream) {
  const float* Uq   = (const float*)d_in[0];
  const float* Uid  = (const float*)d_in[1];
  const float* mask = (const float*)d_in[2];
  const float* Wcw  = (const float*)d_in[3];
  const float* Wcb  = (const float*)d_in[4];
  float* out = (float*)d_out;

  char* ws = (char*)d_ws;
  size_t off = 0;
  auto alloc = [&](size_t bytes) -> void* {
    void* p = ws + off; off += (bytes + 255) & ~(size_t)255; return p;
  };
  const size_t nUb = (size_t)NB * L * E * 2;
  ushort* UqB   = (ushort*)alloc(nUb);
  ushort* UidB  = (ushort*)alloc(nUb);
  ushort* Uidw  = (ushort*)alloc(nUb);
  ushort* UqT   = (ushort*)alloc(nUb);
  ushort* UidT  = (ushort*)alloc(nUb);
  ushort* Tt    = (ushort*)alloc(nUb);
  ushort* maskT = (ushort*)alloc((size_t)L * L * 2);
  float*  s_id  = (float*)alloc((size_t)NB * L * 4);
  float*  s_q   = (float*)alloc((size_t)NB * L * 4);
  // fixed ~34 MB; chunk: St + P each nb_c * 8.4 MB
  const size_t per_batch = (size_t)L * L * 2;
  size_t avail = (ws_size > off + 2 * per_batch) ? (ws_size - off) : 2 * per_batch;
  int nb_c = (int)(avail / (2 * per_batch));
  if (nb_c < 1) nb_c = 1;
  if (nb_c > NB) nb_c = NB;
  ushort* St = (ushort*)(ws + off);                      // becomes Pt in place
  ushort* P  = (ushort*)(ws + off + nb_c * per_batch);

  dim3 tb(32, 8);
  k_prep<<<NB * L, E, 0, stream>>>(Uq, Uid, Wcw, UqB, UidB, Uidw, s_id, s_q);
  k_maskT<<<dim3(L / 32, L / 32), tb, 0, stream>>>(mask, maskT);
  k_tr<<<dim3(E / 32, L / 32, NB), tb, 0, stream>>>(UqB, UqT, L, E);
  k_tr<<<dim3(E / 32, L / 32, NB), tb, 0, stream>>>(UidB, UidT, L, E);

  for (int b0 = 0; b0 < NB; b0 += nb_c) {
    int nb = (NB - b0 < nb_c) ? (NB - b0) : nb_c;
    k_scores<<<dim3(L / 128, L / 128, nb), 256, 0, stream>>>(UqB, Uidw, s_id, s_q, Wcb, maskT, St, b0);
    k_softmax_tr<<<dim3(L / 32, nb), 256, 0, stream>>>(St, P);       // St->Pt, +P
    k_gemm_Tt<<<dim3(2 * (L / 128), 1, nb), 256, 0, stream>>>(UidT, St, Tt, b0);
    k_gemm_A<<<dim3(L / 64, 2, nb), 256, 0, stream>>>(P, UqT, Tt, UidB, out, b0);
  }
}